// Round 2
// 272.137 us; speedup vs baseline: 1.0052x; 1.0052x over previous
//
#include <hip/hip_runtime.h>

// CRF loss (torchcrf semantics) for B=512, T=4096, L=15, mask = all-ones.
//
// Transposed linear-space recurrence, LDS-free inner loop:
//   S <- diag(E_t) * W^T * S,  S_init = I,  W = exp(trans), E_t = exp(em_t).
// MFMA trick: state rows i live at k-slots phi(i)=8*(i>>2)+(i&3); A columns at
// the other 16 k-slots are zero. B-frag elem j of lane (q,c) is this lane's
// own D-frag d[j] (j<4): D->B conversion = 2 v_perm packs, no cross-lane.
// Renorm every 8 steps: read lane0 d[0] exponent (readfirstlane + scalar ops),
// fold 2^-K into the next step's exp2 argument (free fma addend), accumulate
// integer sum(K). Zero cross-lane ops, zero lgkm waits, exact bookkeeping.
//
// v2: the previous version kept eb[8]/ebn[8] as address-taken C arrays
// (lambda float* param) -> never promoted to VGPRs (VGPR_Count=28!), so the
// "double buffer" was illusory and every round exposed ~full HBM latency
// (1107 cyc/step measured, all pipes ~12% busy). Now: named f32x8 register
// buffers, literal element indices, macro bodies, QUAD buffering (prefetch
// distance = 2 rounds). Identical arithmetic order -> bit-identical result.
// (Resubmitted unchanged: round-1 bench was an infra container failure.)

typedef __attribute__((ext_vector_type(8))) __bf16 bf16x8;
typedef __attribute__((ext_vector_type(8))) float f32x8;
typedef __attribute__((ext_vector_type(4))) float f32x4;
typedef __attribute__((ext_vector_type(4))) int   i32x4;
typedef __attribute__((ext_vector_type(2))) float f32x2;

#define BATCH 512
#define TLEN  4096
#define NCH   16
#define CLEN  256
#define LOG2E 1.44269504088896340736f
#define LN2   0.69314718055994530942f

// pack two f32 into one dword of two bf16 (truncation); lo in low half
__device__ __forceinline__ int pack_bf16_pair(float lo, float hi){
  return __builtin_amdgcn_perm(__float_as_uint(hi), __float_as_uint(lo), 0x07060302);
}

__global__ __launch_bounds__(256) void crf_chunk_kernel(
    const float* __restrict__ em, const float* __restrict__ trans,
    const int* __restrict__ labels,
    float* __restrict__ wsM, float* __restrict__ wsS, float* __restrict__ wsNum)
{
  const int tid   = threadIdx.x;
  const int lane  = tid & 63;
  const int col   = lane & 15;              // state column n / A-row m
  const int g     = lane >> 4;              // lane quad
  const int wid   = blockIdx.x * 4 + (tid >> 6);
  const int b     = wid >> 4;
  const int c     = wid & (NCH - 1);
  const int t0    = 1 + c * CLEN;
  const int colc  = (col < 15) ? col : 14;
  const long bT   = (long)b * TLEN;

  const float* emb = em + (bT + t0) * 15 + colc;

  // ---------------- numerator prologue (vectorized, once per wave) ----------
  {
    const int tA = c * CLEN + lane * 4;
    const int4 lv = *reinterpret_cast<const int4*>(labels + bT + tA);
    const int lpm1 = __shfl(lv.w, lane - 1);   // labels[tA-1]; lane0 unused
    const float* emA = em + (bT + tA) * 15;
    float a = 0.f;
    float a0 = emA[lv.x] + trans[lpm1 * 15 + lv.x];
    if (lane > 0) a += a0;
    a += emA[15 + lv.y] + trans[lv.x * 15 + lv.y];
    a += emA[30 + lv.z] + trans[lv.y * 15 + lv.z];
    a += emA[45 + lv.w] + trans[lv.z * 15 + lv.w];
    if (lane == 63 && c < NCH - 1){
      const int te = (c + 1) * CLEN;
      const int le = labels[bT + te];
      a += em[(bT + te) * 15 + le] + trans[lv.w * 15 + le];
    }
    #pragma unroll
    for (int off = 1; off < 64; off <<= 1) a += __shfl_xor(a, off);
    if (lane == 0) wsNum[wid] = a;
  }

  // A-operand constants: wa[j] = W[4g+j][col] = W^T row col
  f32x2 wa01, wa23;
  {
    float wv[4];
    #pragma unroll
    for (int j = 0; j < 4; ++j){
      const int row = 4 * g + j;
      wv[j] = (row < 15 && col < 15)
            ? __builtin_amdgcn_exp2f(trans[row * 15 + col] * LOG2E) : 0.f;
    }
    wa01[0] = wv[0]; wa01[1] = wv[1]; wa23[0] = wv[2]; wa23[1] = wv[3];
  }

  f32x4 d;                                   // state: d[r] = S[4g+r][col]
  #pragma unroll
  for (int r = 0; r < 4; ++r) d[r] = (4 * g + r == col) ? 1.f : 0.f;  // S = I

  const f32x4 zero4 = {0.f, 0.f, 0.f, 0.f};
  int Ki = 0;                                // accumulated log2 scale (exact)

  // quad emission register buffers — literal indices only (must stay in VGPRs)
  f32x8 e0, e1, e2, e3;

#define LOADE(buf, rr) { const float* _p = emb + (rr) * 120;            \
    buf[0] = _p[0];   buf[1] = _p[15];  buf[2] = _p[30];  buf[3] = _p[45]; \
    buf[4] = _p[60];  buf[5] = _p[75];  buf[6] = _p[90];  buf[7] = _p[105]; }

#define LOADE7(buf) { const float* _p = emb + 31 * 120;                 \
    buf[0] = _p[0];   buf[1] = _p[15];  buf[2] = _p[30];  buf[3] = _p[45]; \
    buf[4] = _p[60];  buf[5] = _p[75];  buf[6] = _p[90]; }

#define STEP1(XV) {                                                     \
    const float _E = __builtin_amdgcn_exp2f(XV);                        \
    const f32x2 _e01 = wa01 * _E, _e23 = wa23 * _E;                     \
    i32x4 _ai; _ai[0] = pack_bf16_pair(_e01[0], _e01[1]);               \
               _ai[1] = pack_bf16_pair(_e23[0], _e23[1]);               \
               _ai[2] = 0; _ai[3] = 0;                                  \
    i32x4 _bi; _bi[0] = pack_bf16_pair(d[0], d[1]);                     \
               _bi[1] = pack_bf16_pair(d[2], d[3]);                     \
               _bi[2] = 0; _bi[3] = 0;                                  \
    d = __builtin_amdgcn_mfma_f32_16x16x32_bf16(                        \
          __builtin_bit_cast(bf16x8, _ai), __builtin_bit_cast(bf16x8, _bi), \
          zero4, 0, 0, 0); }

#define BODY8(EB, RN) {                                                 \
    float _add = 0.f;                                                   \
    if (RN) { const int _bits =                                         \
                __builtin_amdgcn_readfirstlane(__float_as_int(d[0]));   \
              const int _K = ((_bits >> 23) & 0xff) - 127;              \
              Ki += _K; _add = (float)(-_K); }                          \
    STEP1(__builtin_fmaf(EB[0], LOG2E, _add));                          \
    STEP1(EB[1] * LOG2E); STEP1(EB[2] * LOG2E); STEP1(EB[3] * LOG2E);   \
    STEP1(EB[4] * LOG2E); STEP1(EB[5] * LOG2E); STEP1(EB[6] * LOG2E);   \
    STEP1(EB[7] * LOG2E); }

#define BODY7(EB) {                                                     \
    const int _bits = __builtin_amdgcn_readfirstlane(__float_as_int(d[0])); \
    const int _K = ((_bits >> 23) & 0xff) - 127;                        \
    Ki += _K; const float _add = (float)(-_K);                          \
    STEP1(__builtin_fmaf(EB[0], LOG2E, _add));                          \
    STEP1(EB[1] * LOG2E); STEP1(EB[2] * LOG2E); STEP1(EB[3] * LOG2E);   \
    STEP1(EB[4] * LOG2E); STEP1(EB[5] * LOG2E); STEP1(EB[6] * LOG2E); }

  LOADE(e0, 0);                              // prefetch distance = 2 rounds
  LOADE(e1, 1);

  if (c != NCH - 1){                         // 256 steps = 32 rounds
    #pragma unroll 1
    for (int rr = 0; rr < 8; ++rr){
      LOADE(e2, 4 * rr + 2); BODY8(e0, rr != 0);
      LOADE(e3, 4 * rr + 3); BODY8(e1, 1);
      LOADE(e0, 4 * rr + 4); BODY8(e2, 1);   // rr=7: over-issue rounds 32/33,
      LOADE(e1, 4 * rr + 5); BODY8(e3, 1);   // in-bounds for c<15 (t<=4096)
    }
  } else {                                   // 255 steps = 31 rounds + 7 tail
    #pragma unroll 1
    for (int rr = 0; rr < 7; ++rr){          // bodies: rounds 0..27
      LOADE(e2, 4 * rr + 2); BODY8(e0, rr != 0);
      LOADE(e3, 4 * rr + 3); BODY8(e1, 1);
      LOADE(e0, 4 * rr + 4); BODY8(e2, 1);   // issues up to round 29 (valid)
      LOADE(e1, 4 * rr + 5); BODY8(e3, 1);
    }
    LOADE(e2, 30); BODY8(e0, 1);             // round 28
    LOADE7(e3);    BODY8(e1, 1);             // round 29; tail data -> e3
    BODY8(e2, 1);                            // round 30
    BODY7(e3);                               // tail: 7 steps, renorm at start
  }

#undef LOADE
#undef LOADE7
#undef STEP1
#undef BODY8
#undef BODY7

  // store S rows: wsM[wid*256 + lane*4 + r] = S[4g+r][col]
  *reinterpret_cast<f32x4*>(wsM + (long)wid * 256 + lane * 4) = d;
  if (lane == 0) wsS[wid] = (float)Ki;       // chunk log2-scale (exact integer)
}

__global__ __launch_bounds__(64) void crf_combine_kernel(
    const float* __restrict__ em, const float* __restrict__ startT,
    const float* __restrict__ endT, const int* __restrict__ labels,
    const float* __restrict__ wsM, const float* __restrict__ wsS,
    const float* __restrict__ wsNum, float* __restrict__ out)
{
  const int lane = threadIdx.x;              // one 64-lane wave per block
  const int b = blockIdx.x;                  // one wave per batch row
  const int n = lane & 15;                   // state index (15 = pad)
  const int nc = (n < 15) ? n : 0;
  const long bT = (long)b * TLEN;

  // alpha0 (column vector v), replicated across the 4 quads
  float v = (n < 15)
          ? __builtin_amdgcn_exp2f((startT[nc] + em[bT * 15 + nc]) * LOG2E) : 0.f;
  float ST = 0.f;

  // numerator: sum the 16 per-chunk partials (n indexes chunks here)
  float np = wsNum[b * NCH + n];
  #pragma unroll
  for (int off = 1; off < 16; off <<= 1) np += __shfl_xor(np, off);

  const int srcl = 16 * (n >> 2) + n;       // lane holding y_n after select

  const float* mp = wsM + (long)(b * NCH) * 256 + lane * 4;
  f32x4 nm = *reinterpret_cast<const f32x4*>(mp);   // prefetched chunk matrix

  for (int c = 0; c < NCH; ++c){
    const f32x4 m4 = nm;
    const int cn = (c < NCH - 1) ? (c + 1) : (NCH - 1);
    nm = *reinterpret_cast<const f32x4*>(mp + (long)cn * 256);  // prefetch next
    float p0 = m4[0] * v, p1 = m4[1] * v, p2 = m4[2] * v, p3 = m4[3] * v;
    #pragma unroll
    for (int off = 1; off < 16; off <<= 1){  // reduce over columns (16 lanes)
      p0 += __shfl_xor(p0, off); p1 += __shfl_xor(p1, off);
      p2 += __shfl_xor(p2, off); p3 += __shfl_xor(p3, off);
    }
    const float ysel = (n & 2) ? ((n & 1) ? p3 : p2) : ((n & 1) ? p1 : p0);
    v = __shfl(ysel, srcl);                  // v_n = y_n on every lane
    ST += wsS[b * NCH + c];                  // chunk log2 scale
    float mx = v;
    #pragma unroll
    for (int off = 1; off < 16; off <<= 1) mx = fmaxf(mx, __shfl_xor(mx, off));
    v *= __builtin_amdgcn_rcpf(mx);
    ST += __builtin_amdgcn_logf(mx);         // v_log_f32 = log2
  }

  float w = (n < 15) ? v * __builtin_amdgcn_exp2f(endT[nc] * LOG2E) : 0.f;
  #pragma unroll
  for (int off = 1; off < 16; off <<= 1) w += __shfl_xor(w, off);

  if (lane == 0){
    const float den = (__builtin_amdgcn_logf(w) + ST) * LN2;
    const int l0 = labels[bT];
    const int lT = labels[bT + TLEN - 1];
    const float num = np + startT[l0] + em[bT * 15 + l0] + endT[lT];
    atomicAdd(out, (den - num) * (1.0f / BATCH));      // loss = mean(den - num)
  }
}

extern "C" void kernel_launch(void* const* d_in, const int* in_sizes, int n_in,
                              void* d_out, int out_size, void* d_ws, size_t ws_size,
                              hipStream_t stream)
{
  const float* em     = (const float*)d_in[0];
  const float* trans  = (const float*)d_in[1];
  const float* startT = (const float*)d_in[2];
  const float* endT   = (const float*)d_in[3];
  const int*   labels = (const int*)d_in[4];
  // d_in[5] = mask: all-ones per setup_inputs (unused)
  float* out = (float*)d_out;

  float* wsNum = (float*)d_ws;                                // 8192 floats
  float* wsS   = (float*)((char*)d_ws + 32768);               // 8192 floats
  float* wsM   = (float*)((char*)d_ws + 65536);               // 8192*256 floats

  hipMemsetAsync(d_out, 0, sizeof(float), stream);

  crf_chunk_kernel<<<BATCH * NCH / 4, 256, 0, stream>>>(em, trans, labels, wsM, wsS, wsNum);
  crf_combine_kernel<<<BATCH, 64, 0, stream>>>(em, startT, endT, labels, wsM, wsS, wsNum, out);
}

// Round 3
// 267.207 us; speedup vs baseline: 1.0237x; 1.0184x over previous
//
#include <hip/hip_runtime.h>

// CRF loss (torchcrf semantics) for B=512, T=4096, L=15, mask = all-ones.
//
// Transposed linear-space recurrence, LDS-free inner loop:
//   S <- diag(E_t) * W^T * S,  S_init = I,  W = exp(trans), E_t = exp(em_t).
// MFMA trick: state rows i live at k-slots phi(i)=8*(i>>2)+(i&3); A columns at
// the other 16 k-slots are zero. B-frag elem j of lane (q,c) is this lane's
// own D-frag d[j] (j<4): D->B conversion = 2 v_perm packs, no cross-lane.
// Renorm every 8 steps: read lane0 d[0] exponent (readfirstlane + scalar ops),
// fold 2^-K into the next step's exp2 argument (free fma addend), accumulate
// integer sum(K). Zero cross-lane ops, zero lgkm waits, exact bookkeeping.
//
// v3: v2's named f32x8 buffers STILL got their loads sunk by the machine
// scheduler (VGPR_Count=32 -> buffers not live, dur unchanged at ~120us,
// 140 cyc/step = one exposed HBM latency per 8-step round). The whole
// unrolled body is one BB and LLVM re-sinks loads to shrink live ranges.
// Fix: __builtin_amdgcn_sched_barrier(0) after every LOADE partitions the
// BB so loads cannot sink -> true distance-2 prefetch (vmcnt(16) steady
// state). __launch_bounds__(256,8) pins the allocator below the 64-VGPR /
// 8-wave occupancy cliff. Combine kernel: preload ALL 16 chunk matrices +
// scales into registers up front (batched loads), zero memory latency in
// the 16-deep serial merge chain. Arithmetic order is bit-identical to v2.

typedef __attribute__((ext_vector_type(8))) __bf16 bf16x8;
typedef __attribute__((ext_vector_type(8))) float f32x8;
typedef __attribute__((ext_vector_type(4))) float f32x4;
typedef __attribute__((ext_vector_type(4))) int   i32x4;
typedef __attribute__((ext_vector_type(2))) float f32x2;

#define BATCH 512
#define TLEN  4096
#define NCH   16
#define CLEN  256
#define LOG2E 1.44269504088896340736f
#define LN2   0.69314718055994530942f

#define SB() __builtin_amdgcn_sched_barrier(0)

// pack two f32 into one dword of two bf16 (truncation); lo in low half
__device__ __forceinline__ int pack_bf16_pair(float lo, float hi){
  return __builtin_amdgcn_perm(__float_as_uint(hi), __float_as_uint(lo), 0x07060302);
}

__global__ __launch_bounds__(256, 8) void crf_chunk_kernel(
    const float* __restrict__ em, const float* __restrict__ trans,
    const int* __restrict__ labels,
    float* __restrict__ wsM, float* __restrict__ wsS, float* __restrict__ wsNum)
{
  const int tid   = threadIdx.x;
  const int lane  = tid & 63;
  const int col   = lane & 15;              // state column n / A-row m
  const int g     = lane >> 4;              // lane quad
  const int wid   = blockIdx.x * 4 + (tid >> 6);
  const int b     = wid >> 4;
  const int c     = wid & (NCH - 1);
  const int t0    = 1 + c * CLEN;
  const int colc  = (col < 15) ? col : 14;
  const long bT   = (long)b * TLEN;

  const float* emb = em + (bT + t0) * 15 + colc;

  // quad emission register buffers — literal indices only (must stay in VGPRs)
  f32x8 e0, e1, e2, e3;

#define LOADE(buf, rr) { const float* _p = emb + (rr) * 120;            \
    buf[0] = _p[0];   buf[1] = _p[15];  buf[2] = _p[30];  buf[3] = _p[45]; \
    buf[4] = _p[60];  buf[5] = _p[75];  buf[6] = _p[90];  buf[7] = _p[105]; }

#define LOADE7(buf) { const float* _p = emb + 31 * 120;                 \
    buf[0] = _p[0];   buf[1] = _p[15];  buf[2] = _p[30];  buf[3] = _p[45]; \
    buf[4] = _p[60];  buf[5] = _p[75];  buf[6] = _p[90]; }

  LOADE(e0, 0);                              // in flight before everything else
  LOADE(e1, 1);
  SB();                                      // pin: these may not sink

  // ---------------- numerator prologue (vectorized, once per wave) ----------
  {
    const int tA = c * CLEN + lane * 4;
    const int4 lv = *reinterpret_cast<const int4*>(labels + bT + tA);
    const int lpm1 = __shfl(lv.w, lane - 1);   // labels[tA-1]; lane0 unused
    const float* emA = em + (bT + tA) * 15;
    float a = 0.f;
    float a0 = emA[lv.x] + trans[lpm1 * 15 + lv.x];
    if (lane > 0) a += a0;
    a += emA[15 + lv.y] + trans[lv.x * 15 + lv.y];
    a += emA[30 + lv.z] + trans[lv.y * 15 + lv.z];
    a += emA[45 + lv.w] + trans[lv.z * 15 + lv.w];
    if (lane == 63 && c < NCH - 1){
      const int te = (c + 1) * CLEN;
      const int le = labels[bT + te];
      a += em[(bT + te) * 15 + le] + trans[lv.w * 15 + le];
    }
    #pragma unroll
    for (int off = 1; off < 64; off <<= 1) a += __shfl_xor(a, off);
    if (lane == 0) wsNum[wid] = a;
  }

  // A-operand constants: wa[j] = W[4g+j][col] = W^T row col
  f32x2 wa01, wa23;
  {
    float wv[4];
    #pragma unroll
    for (int j = 0; j < 4; ++j){
      const int row = 4 * g + j;
      wv[j] = (row < 15 && col < 15)
            ? __builtin_amdgcn_exp2f(trans[row * 15 + col] * LOG2E) : 0.f;
    }
    wa01[0] = wv[0]; wa01[1] = wv[1]; wa23[0] = wv[2]; wa23[1] = wv[3];
  }

  f32x4 d;                                   // state: d[r] = S[4g+r][col]
  #pragma unroll
  for (int r = 0; r < 4; ++r) d[r] = (4 * g + r == col) ? 1.f : 0.f;  // S = I

  const f32x4 zero4 = {0.f, 0.f, 0.f, 0.f};
  int Ki = 0;                                // accumulated log2 scale (exact)

#define STEP1(XV) {                                                     \
    const float _E = __builtin_amdgcn_exp2f(XV);                        \
    const f32x2 _e01 = wa01 * _E, _e23 = wa23 * _E;                     \
    i32x4 _ai; _ai[0] = pack_bf16_pair(_e01[0], _e01[1]);               \
               _ai[1] = pack_bf16_pair(_e23[0], _e23[1]);               \
               _ai[2] = 0; _ai[3] = 0;                                  \
    i32x4 _bi; _bi[0] = pack_bf16_pair(d[0], d[1]);                     \
               _bi[1] = pack_bf16_pair(d[2], d[3]);                     \
               _bi[2] = 0; _bi[3] = 0;                                  \
    d = __builtin_amdgcn_mfma_f32_16x16x32_bf16(                        \
          __builtin_bit_cast(bf16x8, _ai), __builtin_bit_cast(bf16x8, _bi), \
          zero4, 0, 0, 0); }

#define BODY8(EB, RN) {                                                 \
    float _add = 0.f;                                                   \
    if (RN) { const int _bits =                                         \
                __builtin_amdgcn_readfirstlane(__float_as_int(d[0]));   \
              const int _K = ((_bits >> 23) & 0xff) - 127;              \
              Ki += _K; _add = (float)(-_K); }                          \
    STEP1(__builtin_fmaf(EB[0], LOG2E, _add));                          \
    STEP1(EB[1] * LOG2E); STEP1(EB[2] * LOG2E); STEP1(EB[3] * LOG2E);   \
    STEP1(EB[4] * LOG2E); STEP1(EB[5] * LOG2E); STEP1(EB[6] * LOG2E);   \
    STEP1(EB[7] * LOG2E); }

#define BODY7(EB) {                                                     \
    const int _bits = __builtin_amdgcn_readfirstlane(__float_as_int(d[0])); \
    const int _K = ((_bits >> 23) & 0xff) - 127;                        \
    Ki += _K; const float _add = (float)(-_K);                          \
    STEP1(__builtin_fmaf(EB[0], LOG2E, _add));                          \
    STEP1(EB[1] * LOG2E); STEP1(EB[2] * LOG2E); STEP1(EB[3] * LOG2E);   \
    STEP1(EB[4] * LOG2E); STEP1(EB[5] * LOG2E); STEP1(EB[6] * LOG2E); }

  if (c != NCH - 1){                         // 256 steps = 32 rounds
    #pragma unroll 1
    for (int rr = 0; rr < 8; ++rr){
      LOADE(e2, 4 * rr + 2); SB(); BODY8(e0, rr != 0);
      LOADE(e3, 4 * rr + 3); SB(); BODY8(e1, 1);
      LOADE(e0, 4 * rr + 4); SB(); BODY8(e2, 1);  // rr=7: over-issues rounds
      LOADE(e1, 4 * rr + 5); SB(); BODY8(e3, 1);  // 32/33 — in-bounds for c<15
    }
  } else {                                   // 255 steps = 31 rounds + 7 tail
    #pragma unroll 1
    for (int rr = 0; rr < 7; ++rr){          // bodies: rounds 0..27
      LOADE(e2, 4 * rr + 2); SB(); BODY8(e0, rr != 0);
      LOADE(e3, 4 * rr + 3); SB(); BODY8(e1, 1);
      LOADE(e0, 4 * rr + 4); SB(); BODY8(e2, 1);  // issues up to round 29 (ok)
      LOADE(e1, 4 * rr + 5); SB(); BODY8(e3, 1);
    }
    LOADE(e2, 30); SB(); BODY8(e0, 1);       // round 28
    LOADE7(e3);    SB(); BODY8(e1, 1);       // round 29; tail data -> e3
    BODY8(e2, 1);                            // round 30
    BODY7(e3);                               // tail: 7 steps, renorm at start
  }

#undef LOADE
#undef LOADE7
#undef STEP1
#undef BODY8
#undef BODY7

  // store S rows: wsM[wid*256 + lane*4 + r] = S[4g+r][col]
  *reinterpret_cast<f32x4*>(wsM + (long)wid * 256 + lane * 4) = d;
  if (lane == 0) wsS[wid] = (float)Ki;       // chunk log2-scale (exact integer)
}

__global__ __launch_bounds__(64) void crf_combine_kernel(
    const float* __restrict__ em, const float* __restrict__ startT,
    const float* __restrict__ endT, const int* __restrict__ labels,
    const float* __restrict__ wsM, const float* __restrict__ wsS,
    const float* __restrict__ wsNum, float* __restrict__ out)
{
  const int lane = threadIdx.x;              // one 64-lane wave per block
  const int b = blockIdx.x;                  // one wave per batch row
  const int n = lane & 15;                   // state index (15 = pad)
  const int nc = (n < 15) ? n : 0;
  const long bT = (long)b * TLEN;

  // preload ALL 16 chunk matrices (batched, all in flight) + scales
  const float* mp = wsM + (long)(b * NCH) * 256 + lane * 4;
  const float* sp = wsS + b * NCH;
#define LDM(c) *reinterpret_cast<const f32x4*>(mp + (c) * 256)
  f32x4 M0 = LDM(0),  M1 = LDM(1),  M2 = LDM(2),  M3 = LDM(3);
  f32x4 M4 = LDM(4),  M5 = LDM(5),  M6 = LDM(6),  M7 = LDM(7);
  f32x4 M8 = LDM(8),  M9 = LDM(9),  M10 = LDM(10), M11 = LDM(11);
  f32x4 M12 = LDM(12), M13 = LDM(13), M14 = LDM(14), M15 = LDM(15);
#undef LDM
  const float S0 = sp[0],  S1 = sp[1],  S2 = sp[2],  S3 = sp[3];
  const float S4 = sp[4],  S5 = sp[5],  S6 = sp[6],  S7 = sp[7];
  const float S8 = sp[8],  S9 = sp[9],  S10 = sp[10], S11 = sp[11];
  const float S12 = sp[12], S13 = sp[13], S14 = sp[14], S15 = sp[15];

  // alpha0 (column vector v), replicated across the 4 quads
  float v = (n < 15)
          ? __builtin_amdgcn_exp2f((startT[nc] + em[bT * 15 + nc]) * LOG2E) : 0.f;
  float ST = 0.f;

  // numerator: sum the 16 per-chunk partials (n indexes chunks here)
  float np = wsNum[b * NCH + n];
  #pragma unroll
  for (int off = 1; off < 16; off <<= 1) np += __shfl_xor(np, off);

  const int srcl = 16 * (n >> 2) + n;       // lane holding y_n after select

#define CITER(MC, SC) {                                                 \
    float p0 = MC[0] * v, p1 = MC[1] * v, p2 = MC[2] * v, p3 = MC[3] * v; \
    _Pragma("unroll")                                                   \
    for (int off = 1; off < 16; off <<= 1){  /* reduce over 16 columns */ \
      p0 += __shfl_xor(p0, off); p1 += __shfl_xor(p1, off);             \
      p2 += __shfl_xor(p2, off); p3 += __shfl_xor(p3, off);             \
    }                                                                   \
    const float ysel = (n & 2) ? ((n & 1) ? p3 : p2) : ((n & 1) ? p1 : p0); \
    v = __shfl(ysel, srcl);                  /* v_n = y_n on every lane */ \
    ST += SC;                                /* chunk log2 scale */     \
    float mx = v;                                                       \
    _Pragma("unroll")                                                   \
    for (int off = 1; off < 16; off <<= 1) mx = fmaxf(mx, __shfl_xor(mx, off)); \
    v *= __builtin_amdgcn_rcpf(mx);                                     \
    ST += __builtin_amdgcn_logf(mx); }       /* v_log_f32 = log2 */

  CITER(M0, S0);   CITER(M1, S1);   CITER(M2, S2);   CITER(M3, S3);
  CITER(M4, S4);   CITER(M5, S5);   CITER(M6, S6);   CITER(M7, S7);
  CITER(M8, S8);   CITER(M9, S9);   CITER(M10, S10); CITER(M11, S11);
  CITER(M12, S12); CITER(M13, S13); CITER(M14, S14); CITER(M15, S15);
#undef CITER

  float w = (n < 15) ? v * __builtin_amdgcn_exp2f(endT[nc] * LOG2E) : 0.f;
  #pragma unroll
  for (int off = 1; off < 16; off <<= 1) w += __shfl_xor(w, off);

  if (lane == 0){
    const float den = (__builtin_amdgcn_logf(w) + ST) * LN2;
    const int l0 = labels[bT];
    const int lT = labels[bT + TLEN - 1];
    const float num = np + startT[l0] + em[bT * 15 + l0] + endT[lT];
    atomicAdd(out, (den - num) * (1.0f / BATCH));      // loss = mean(den - num)
  }
}

extern "C" void kernel_launch(void* const* d_in, const int* in_sizes, int n_in,
                              void* d_out, int out_size, void* d_ws, size_t ws_size,
                              hipStream_t stream)
{
  const float* em     = (const float*)d_in[0];
  const float* trans  = (const float*)d_in[1];
  const float* startT = (const float*)d_in[2];
  const float* endT   = (const float*)d_in[3];
  const int*   labels = (const int*)d_in[4];
  // d_in[5] = mask: all-ones per setup_inputs (unused)
  float* out = (float*)d_out;

  float* wsNum = (float*)d_ws;                                // 8192 floats
  float* wsS   = (float*)((char*)d_ws + 32768);               // 8192 floats
  float* wsM   = (float*)((char*)d_ws + 65536);               // 8192*256 floats

  hipMemsetAsync(d_out, 0, sizeof(float), stream);

  crf_chunk_kernel<<<BATCH * NCH / 4, 256, 0, stream>>>(em, trans, labels, wsM, wsS, wsNum);
  crf_combine_kernel<<<BATCH, 64, 0, stream>>>(em, startT, endT, labels, wsM, wsS, wsNum, out);
}

// Round 4
// 260.754 us; speedup vs baseline: 1.0490x; 1.0247x over previous
//
#include <hip/hip_runtime.h>

// CRF loss (torchcrf semantics) for B=512, T=4096, L=15, mask = all-ones.
//
// Transposed linear-space recurrence, LDS-free inner loop:
//   S <- diag(E_t) * W^T * S,  S_init = I,  W = exp(trans), E_t = exp(em_t).
// MFMA trick: state rows i live at k-slots phi(i)=8*(i>>2)+(i&3); A columns at
// the other 16 k-slots are zero. B-frag elem j of lane (q,c) is this lane's
// own D-frag d[j] (j<4): D->B conversion = 2 v_perm packs, no cross-lane.
// Renorm every 8 steps: read lane0 d[0] exponent (readfirstlane + scalar ops),
// fold 2^-K into the next step's exp2 argument (free fma addend), accumulate
// integer sum(K). Zero cross-lane ops, exact bookkeeping.
//
// v4: v2/v3 proved compiler-generated loads CANNOT be kept in flight from
// HIP source (VGPR_Count=28 both rounds; loads sunk to uses at DAG/IR level,
// sched_barrier only constrains the MachineScheduler). 132 cyc/step-slot vs
// ~20 cyc of issue work = ~85% exposed HBM latency. Fix: inline-asm
// global_load_dword into named scalar float registers (opaque to every
// scheduler pass) + manual counted s_waitcnt vmcnt(16) (AITER-style, never 0
// in the loop; 24 loads outstanding at each wait, in-order retirement frees
// exactly the consumed buffer). sched_barrier(0) after each waitcnt per
// rule #18. Arithmetic order bit-identical to v0-v3.

typedef __attribute__((ext_vector_type(8))) __bf16 bf16x8;
typedef __attribute__((ext_vector_type(4))) float f32x4;
typedef __attribute__((ext_vector_type(4))) int   i32x4;
typedef __attribute__((ext_vector_type(2))) float f32x2;

#define BATCH 512
#define TLEN  4096
#define NCH   16
#define CLEN  256
#define LOG2E 1.44269504088896340736f
#define LN2   0.69314718055994530942f

// pack two f32 into one dword of two bf16 (truncation); lo in low half
__device__ __forceinline__ int pack_bf16_pair(float lo, float hi){
  return __builtin_amdgcn_perm(__float_as_uint(hi), __float_as_uint(lo), 0x07060302);
}

__global__ __launch_bounds__(256, 8) void crf_chunk_kernel(
    const float* __restrict__ em, const float* __restrict__ trans,
    const int* __restrict__ labels,
    float* __restrict__ wsM, float* __restrict__ wsS, float* __restrict__ wsNum)
{
  const int tid   = threadIdx.x;
  const int lane  = tid & 63;
  const int col   = lane & 15;              // state column n / A-row m
  const int g     = lane >> 4;              // lane quad
  const int wid   = blockIdx.x * 4 + (tid >> 6);
  const int b     = wid >> 4;
  const int c     = wid & (NCH - 1);
  const int t0    = 1 + c * CLEN;
  const int colc  = (col < 15) ? col : 14;
  const long bT   = (long)b * TLEN;

  const float* emb = em + (bT + t0) * 15 + colc;

  // four 8-float buffers as named scalars — asm outputs, pinned in VGPRs
  float A0,A1,A2,A3,A4,A5,A6,A7;
  float B0,B1,B2,B3,B4,B5,B6,B7;
  float C0,C1,C2,C3,C4,C5,C6,C7;
  float D0,D1,D2,D3,D4,D5,D6,D7;

  // 8 strided dword loads (stride 15 floats = 60 B), opaque to the compiler.
  // Early-clobber outputs so none aliases the address pair.
#define LOAD8(X0,X1,X2,X3,X4,X5,X6,X7, P)                               \
  asm volatile("global_load_dword %0, %8, off\n\t"                      \
               "global_load_dword %1, %8, off offset:60\n\t"            \
               "global_load_dword %2, %8, off offset:120\n\t"           \
               "global_load_dword %3, %8, off offset:180\n\t"           \
               "global_load_dword %4, %8, off offset:240\n\t"           \
               "global_load_dword %5, %8, off offset:300\n\t"           \
               "global_load_dword %6, %8, off offset:360\n\t"           \
               "global_load_dword %7, %8, off offset:420\n\t"           \
               : "=&v"(X0), "=&v"(X1), "=&v"(X2), "=&v"(X3),            \
                 "=&v"(X4), "=&v"(X5), "=&v"(X6), "=&v"(X7)             \
               : "v"(P) : "memory")

#define LOAD7(X0,X1,X2,X3,X4,X5,X6, P)                                  \
  asm volatile("global_load_dword %0, %7, off\n\t"                      \
               "global_load_dword %1, %7, off offset:60\n\t"            \
               "global_load_dword %2, %7, off offset:120\n\t"           \
               "global_load_dword %3, %7, off offset:180\n\t"           \
               "global_load_dword %4, %7, off offset:240\n\t"           \
               "global_load_dword %5, %7, off offset:300\n\t"           \
               "global_load_dword %6, %7, off offset:360\n\t"           \
               : "=&v"(X0), "=&v"(X1), "=&v"(X2), "=&v"(X3),            \
                 "=&v"(X4), "=&v"(X5), "=&v"(X6)                        \
               : "v"(P) : "memory")

#define LDA(rr) LOAD8(A0,A1,A2,A3,A4,A5,A6,A7, emb + (rr) * 120)
#define LDB(rr) LOAD8(B0,B1,B2,B3,B4,B5,B6,B7, emb + (rr) * 120)
#define LDC(rr) LOAD8(C0,C1,C2,C3,C4,C5,C6,C7, emb + (rr) * 120)
#define LDD(rr) LOAD8(D0,D1,D2,D3,D4,D5,D6,D7, emb + (rr) * 120)

  // counted wait: in-order vmcnt retirement frees the oldest (consumed) buffer
#define WCNT(n) { asm volatile("s_waitcnt vmcnt(" #n ")" ::: "memory"); \
                  __builtin_amdgcn_sched_barrier(0); }

  LDA(0);                                    // first 2 rounds in flight ASAP
  LDB(1);

  // ---------------- numerator prologue (vectorized, once per wave) ----------
  // (compiler-inserted waits here under-count our asm loads; vmcnt(N)
  //  semantics make that strictly conservative — over-wait, never under.)
  {
    const int tA = c * CLEN + lane * 4;
    const int4 lv = *reinterpret_cast<const int4*>(labels + bT + tA);
    const int lpm1 = __shfl(lv.w, lane - 1);   // labels[tA-1]; lane0 unused
    const float* emA = em + (bT + tA) * 15;
    float a = 0.f;
    float a0 = emA[lv.x] + trans[lpm1 * 15 + lv.x];
    if (lane > 0) a += a0;
    a += emA[15 + lv.y] + trans[lv.x * 15 + lv.y];
    a += emA[30 + lv.z] + trans[lv.y * 15 + lv.z];
    a += emA[45 + lv.w] + trans[lv.z * 15 + lv.w];
    if (lane == 63 && c < NCH - 1){
      const int te = (c + 1) * CLEN;
      const int le = labels[bT + te];
      a += em[(bT + te) * 15 + le] + trans[lv.w * 15 + le];
    }
    #pragma unroll
    for (int off = 1; off < 64; off <<= 1) a += __shfl_xor(a, off);
    if (lane == 0) wsNum[wid] = a;
  }

  // A-operand constants: wa[j] = W[4g+j][col] = W^T row col
  f32x2 wa01, wa23;
  {
    float wv[4];
    #pragma unroll
    for (int j = 0; j < 4; ++j){
      const int row = 4 * g + j;
      wv[j] = (row < 15 && col < 15)
            ? __builtin_amdgcn_exp2f(trans[row * 15 + col] * LOG2E) : 0.f;
    }
    wa01[0] = wv[0]; wa01[1] = wv[1]; wa23[0] = wv[2]; wa23[1] = wv[3];
  }

  f32x4 d;                                   // state: d[r] = S[4g+r][col]
  #pragma unroll
  for (int r = 0; r < 4; ++r) d[r] = (4 * g + r == col) ? 1.f : 0.f;  // S = I

  const f32x4 zero4 = {0.f, 0.f, 0.f, 0.f};
  int Ki = 0;                                // accumulated log2 scale (exact)

#define STEP1(XV) {                                                     \
    const float _E = __builtin_amdgcn_exp2f(XV);                        \
    const f32x2 _e01 = wa01 * _E, _e23 = wa23 * _E;                     \
    i32x4 _ai; _ai[0] = pack_bf16_pair(_e01[0], _e01[1]);               \
               _ai[1] = pack_bf16_pair(_e23[0], _e23[1]);               \
               _ai[2] = 0; _ai[3] = 0;                                  \
    i32x4 _bi; _bi[0] = pack_bf16_pair(d[0], d[1]);                     \
               _bi[1] = pack_bf16_pair(d[2], d[3]);                     \
               _bi[2] = 0; _bi[3] = 0;                                  \
    d = __builtin_amdgcn_mfma_f32_16x16x32_bf16(                        \
          __builtin_bit_cast(bf16x8, _ai), __builtin_bit_cast(bf16x8, _bi), \
          zero4, 0, 0, 0); }

#define BODY8(X0,X1,X2,X3,X4,X5,X6,X7, RN) {                            \
    float _add = 0.f;                                                   \
    if (RN) { const int _bits =                                         \
                __builtin_amdgcn_readfirstlane(__float_as_int(d[0]));   \
              const int _K = ((_bits >> 23) & 0xff) - 127;              \
              Ki += _K; _add = (float)(-_K); }                          \
    STEP1(__builtin_fmaf(X0, LOG2E, _add));                             \
    STEP1(X1 * LOG2E); STEP1(X2 * LOG2E); STEP1(X3 * LOG2E);            \
    STEP1(X4 * LOG2E); STEP1(X5 * LOG2E); STEP1(X6 * LOG2E);            \
    STEP1(X7 * LOG2E); }

#define BODY7(X0,X1,X2,X3,X4,X5,X6) {                                   \
    const int _bits = __builtin_amdgcn_readfirstlane(__float_as_int(d[0])); \
    const int _K = ((_bits >> 23) & 0xff) - 127;                        \
    Ki += _K; const float _add = (float)(-_K);                          \
    STEP1(__builtin_fmaf(X0, LOG2E, _add));                             \
    STEP1(X1 * LOG2E); STEP1(X2 * LOG2E); STEP1(X3 * LOG2E);            \
    STEP1(X4 * LOG2E); STEP1(X5 * LOG2E); STEP1(X6 * LOG2E); }

#define BA(RN) BODY8(A0,A1,A2,A3,A4,A5,A6,A7, RN)
#define BB(RN) BODY8(B0,B1,B2,B3,B4,B5,B6,B7, RN)
#define BC(RN) BODY8(C0,C1,C2,C3,C4,C5,C6,C7, RN)
#define BD(RN) BODY8(D0,D1,D2,D3,D4,D5,D6,D7, RN)

  if (c != NCH - 1){                         // 256 steps = 32 rounds
    #pragma unroll 1
    for (int rr = 0; rr < 8; ++rr){
      LDC(4 * rr + 2); WCNT(16); BA(rr != 0);
      LDD(4 * rr + 3); WCNT(16); BB(1);
      LDA(4 * rr + 4); WCNT(16); BC(1);      // rr=7: over-issues rounds 32/33,
      LDB(4 * rr + 5); WCNT(16); BD(1);      // in-bounds for c<15 (t<=3856)
    }
  } else {                                   // 255 steps = 31 rounds + 7 tail
    #pragma unroll 1
    for (int rr = 0; rr < 7; ++rr){          // bodies: rounds 0..27
      LDC(4 * rr + 2); WCNT(16); BA(rr != 0);
      LDD(4 * rr + 3); WCNT(16); BB(1);
      LDA(4 * rr + 4); WCNT(16); BC(1);      // issues up to round 29 (valid)
      LDB(4 * rr + 5); WCNT(16); BD(1);
    }
    // after loop: A=r28, B=r29 in flight (16 outstanding)
    LDC(30);                      WCNT(16); BA(1);   // round 28
    LOAD7(D0,D1,D2,D3,D4,D5,D6, emb + 31 * 120);     // tail 7 loads
                                  WCNT(15); BB(1);   // round 29
                                  WCNT(7);  BC(1);   // round 30
                                  WCNT(0);  BODY7(D0,D1,D2,D3,D4,D5,D6);
  }

#undef LOAD8
#undef LOAD7
#undef LDA
#undef LDB
#undef LDC
#undef LDD
#undef WCNT
#undef STEP1
#undef BODY8
#undef BODY7
#undef BA
#undef BB
#undef BC
#undef BD

  // store S rows: wsM[wid*256 + lane*4 + r] = S[4g+r][col]
  *reinterpret_cast<f32x4*>(wsM + (long)wid * 256 + lane * 4) = d;
  if (lane == 0) wsS[wid] = (float)Ki;       // chunk log2-scale (exact integer)
}

__global__ __launch_bounds__(64) void crf_combine_kernel(
    const float* __restrict__ em, const float* __restrict__ startT,
    const float* __restrict__ endT, const int* __restrict__ labels,
    const float* __restrict__ wsM, const float* __restrict__ wsS,
    const float* __restrict__ wsNum, float* __restrict__ out)
{
  const int lane = threadIdx.x;              // one 64-lane wave per block
  const int b = blockIdx.x;                  // one wave per batch row
  const int n = lane & 15;                   // state index (15 = pad)
  const int nc = (n < 15) ? n : 0;
  const long bT = (long)b * TLEN;

  // preload ALL 16 chunk matrices (batched, all in flight) + scales
  const float* mp = wsM + (long)(b * NCH) * 256 + lane * 4;
  const float* sp = wsS + b * NCH;
#define LDM(c) *reinterpret_cast<const f32x4*>(mp + (c) * 256)
  f32x4 M0 = LDM(0),  M1 = LDM(1),  M2 = LDM(2),  M3 = LDM(3);
  f32x4 M4 = LDM(4),  M5 = LDM(5),  M6 = LDM(6),  M7 = LDM(7);
  f32x4 M8 = LDM(8),  M9 = LDM(9),  M10 = LDM(10), M11 = LDM(11);
  f32x4 M12 = LDM(12), M13 = LDM(13), M14 = LDM(14), M15 = LDM(15);
#undef LDM
  const float S0 = sp[0],  S1 = sp[1],  S2 = sp[2],  S3 = sp[3];
  const float S4 = sp[4],  S5 = sp[5],  S6 = sp[6],  S7 = sp[7];
  const float S8 = sp[8],  S9 = sp[9],  S10 = sp[10], S11 = sp[11];
  const float S12 = sp[12], S13 = sp[13], S14 = sp[14], S15 = sp[15];

  // alpha0 (column vector v), replicated across the 4 quads
  float v = (n < 15)
          ? __builtin_amdgcn_exp2f((startT[nc] + em[bT * 15 + nc]) * LOG2E) : 0.f;
  float ST = 0.f;

  // numerator: sum the 16 per-chunk partials (n indexes chunks here)
  float np = wsNum[b * NCH + n];
  #pragma unroll
  for (int off = 1; off < 16; off <<= 1) np += __shfl_xor(np, off);

  const int srcl = 16 * (n >> 2) + n;       // lane holding y_n after select

#define CITER(MC, SC) {                                                 \
    float p0 = MC[0] * v, p1 = MC[1] * v, p2 = MC[2] * v, p3 = MC[3] * v; \
    _Pragma("unroll")                                                   \
    for (int off = 1; off < 16; off <<= 1){  /* reduce over 16 columns */ \
      p0 += __shfl_xor(p0, off); p1 += __shfl_xor(p1, off);             \
      p2 += __shfl_xor(p2, off); p3 += __shfl_xor(p3, off);             \
    }                                                                   \
    const float ysel = (n & 2) ? ((n & 1) ? p3 : p2) : ((n & 1) ? p1 : p0); \
    v = __shfl(ysel, srcl);                  /* v_n = y_n on every lane */ \
    ST += SC;                                /* chunk log2 scale */     \
    float mx = v;                                                       \
    _Pragma("unroll")                                                   \
    for (int off = 1; off < 16; off <<= 1) mx = fmaxf(mx, __shfl_xor(mx, off)); \
    v *= __builtin_amdgcn_rcpf(mx);                                     \
    ST += __builtin_amdgcn_logf(mx); }       /* v_log_f32 = log2 */

  CITER(M0, S0);   CITER(M1, S1);   CITER(M2, S2);   CITER(M3, S3);
  CITER(M4, S4);   CITER(M5, S5);   CITER(M6, S6);   CITER(M7, S7);
  CITER(M8, S8);   CITER(M9, S9);   CITER(M10, S10); CITER(M11, S11);
  CITER(M12, S12); CITER(M13, S13); CITER(M14, S14); CITER(M15, S15);
#undef CITER

  float w = (n < 15) ? v * __builtin_amdgcn_exp2f(endT[nc] * LOG2E) : 0.f;
  #pragma unroll
  for (int off = 1; off < 16; off <<= 1) w += __shfl_xor(w, off);

  if (lane == 0){
    const float den = (__builtin_amdgcn_logf(w) + ST) * LN2;
    const int l0 = labels[bT];
    const int lT = labels[bT + TLEN - 1];
    const float num = np + startT[l0] + em[bT * 15 + l0] + endT[lT];
    atomicAdd(out, (den - num) * (1.0f / BATCH));      // loss = mean(den - num)
  }
}

extern "C" void kernel_launch(void* const* d_in, const int* in_sizes, int n_in,
                              void* d_out, int out_size, void* d_ws, size_t ws_size,
                              hipStream_t stream)
{
  const float* em     = (const float*)d_in[0];
  const float* trans  = (const float*)d_in[1];
  const float* startT = (const float*)d_in[2];
  const float* endT   = (const float*)d_in[3];
  const int*   labels = (const int*)d_in[4];
  // d_in[5] = mask: all-ones per setup_inputs (unused)
  float* out = (float*)d_out;

  float* wsNum = (float*)d_ws;                                // 8192 floats
  float* wsS   = (float*)((char*)d_ws + 32768);               // 8192 floats
  float* wsM   = (float*)((char*)d_ws + 65536);               // 8192*256 floats

  hipMemsetAsync(d_out, 0, sizeof(float), stream);

  crf_chunk_kernel<<<BATCH * NCH / 4, 256, 0, stream>>>(em, trans, labels, wsM, wsS, wsNum);
  crf_combine_kernel<<<BATCH, 64, 0, stream>>>(em, startT, endT, labels, wsM, wsS, wsNum, out);
}